// Round 4
// baseline (162.843 us; speedup 1.0000x reference)
//
#include <hip/hip_runtime.h>

// RandomAttention: B=2, S=2048, NH=8, H=64, NKEYS=64, fp32.
// R4: TWO queries per wave. Lane remap per query: g = lane>>4 (key
// group), c = lane&15 (float4 chunk of the 64-float row); each 16-lane
// group owns one key row per iteration -> every K/V wave-load covers
// 4 full 256B rows. Two independent gather->dot->softmax->PV chains
// live in one basic block; the list scheduler overlaps chain B's
// K-gather with chain A's softmax/PV (ILP by batching - R2/R3 showed
// forcing depth on ONE chain fails: compiler re-sinks prefetches, and
// volatile-asm pipelines spill at the 128-VGPR budget).
//
// Kept from R1: head-major XCD mapping (e = blockIdx.x & 7) pins each
// head's 2MB k+v gather slice in one XCD's 4MB L2 (FETCH 60->16.4MB).
// Kept from R3: exp2-domain softmax (log2e folded into q scale),
// deferred normalization, v_rcp_f32.

#define BB 2
#define SS 2048
#define NHH 8
#define HH 64
#define NKEYS 64

__global__ __launch_bounds__(256, 4) void rand_attn_kernel(
    const float* __restrict__ q, const float* __restrict__ k,
    const float* __restrict__ v, const int* __restrict__ idx,
    float* __restrict__ out) {
  const int warp = threadIdx.x >> 6;
  const int lane = threadIdx.x & 63;
  const int g = lane >> 4;   // key group 0..3 (key n == 4*j + g)
  const int c = lane & 15;   // float4 chunk within the 64-float row

  // Head == XCD (blocks dispatch round-robin over 8 XCDs).
  const int e = blockIdx.x & 7;                    // head
  const int p = ((blockIdx.x >> 3) << 2) + warp;   // query-pair id
  const int bq0 = 2 * p;                           // b*S + s (even)
  const int b = p >> 10;                           // bq0>>11 == p>>10

  const float* kb = k + (size_t)b * (SS * NHH * HH);
  const float* vb = v + (size_t)b * (SS * NHH * HH);
  const float4* kb4 = (const float4*)kb;
  const float4* vb4 = (const float4*)vb;
  const int co = (e << 4) + c;   // within-row float4 offset: e*16 + c

  // q chunks for both queries, pre-scaled into exp2 domain.
  const float qs = 0.125f * 1.44269504088896f;
  float4 q4[2];
#pragma unroll
  for (int qq = 0; qq < 2; ++qq) {
    const float* qrow = q + ((size_t)(bq0 + qq) * NHH + e) * HH;
    q4[qq] = ((const float4*)qrow)[c];
    q4[qq].x *= qs; q4[qq].y *= qs; q4[qq].z *= qs; q4[qq].w *= qs;
  }

  // Lane n holds idx[bq, n] for each query (coalesced 256B loads).
  int myidx[2];
  myidx[0] = idx[(size_t)bq0 * NKEYS + lane];
  myidx[1] = idx[(size_t)(bq0 + 1) * NKEYS + lane];

  // All key-row float4 offsets for both queries.
  int foff[2][16];
#pragma unroll
  for (int qq = 0; qq < 2; ++qq) {
#pragma unroll
    for (int j = 0; j < 16; ++j) {
      const int n = 4 * j + g;
      const int vi = __builtin_amdgcn_ds_bpermute(n << 2, myidx[qq]);
      foff[qq][j] = (vi << 7) + co;
    }
  }

  // Phase 1: K gather + dots for both chains (scheduler interleaves;
  // chain 1's loads hide under chain 0's shuffle-reduce and vice versa).
  float sc[2][16];
#pragma unroll
  for (int qq = 0; qq < 2; ++qq) {
    float4 k4[16];
#pragma unroll
    for (int j = 0; j < 16; ++j) k4[j] = kb4[foff[qq][j]];
#pragma unroll
    for (int j = 0; j < 16; ++j) {
      float t = k4[j].x * q4[qq].x + k4[j].y * q4[qq].y +
                k4[j].z * q4[qq].z + k4[j].w * q4[qq].w;
      t += __shfl_xor(t, 1, 64);   // intra-group (16-lane) reduce: DPP
      t += __shfl_xor(t, 2, 64);
      t += __shfl_xor(t, 4, 64);
      t += __shfl_xor(t, 8, 64);
      sc[qq][j] = t;
    }
  }

  // Phase 2: per chain - V gather, softmax (hides V latency), PV, store.
  // Chain 1's V loads / dots can overlap chain 0's softmax+PV tail.
#pragma unroll
  for (int qq = 0; qq < 2; ++qq) {
    float4 vv[16];
#pragma unroll
    for (int j = 0; j < 16; ++j) vv[j] = vb4[foff[qq][j]];

    // Softmax over all 64 keys (exp2 domain; 16 per lane + cross-group).
    float m = sc[qq][0];
#pragma unroll
    for (int j = 1; j < 16; ++j) m = fmaxf(m, sc[qq][j]);
    m = fmaxf(m, __shfl_xor(m, 16, 64));
    m = fmaxf(m, __shfl_xor(m, 32, 64));
    float ssum = 0.f;
#pragma unroll
    for (int j = 0; j < 16; ++j) {
      sc[qq][j] = exp2f(sc[qq][j] - m);
      ssum += sc[qq][j];
    }
    ssum += __shfl_xor(ssum, 16, 64);
    ssum += __shfl_xor(ssum, 32, 64);
    const float inv = __builtin_amdgcn_rcpf(ssum);  // wave-uniform

    float4 acc = make_float4(0.f, 0.f, 0.f, 0.f);
#pragma unroll
    for (int j = 0; j < 16; ++j) {
      acc.x += sc[qq][j] * vv[j].x;
      acc.y += sc[qq][j] * vv[j].y;
      acc.z += sc[qq][j] * vv[j].z;
      acc.w += sc[qq][j] * vv[j].w;
    }
    // Cross-group sum (xor 16, 32) -> every lane has the full result.
    acc.x += __shfl_xor(acc.x, 16, 64);
    acc.y += __shfl_xor(acc.y, 16, 64);
    acc.z += __shfl_xor(acc.z, 16, 64);
    acc.w += __shfl_xor(acc.w, 16, 64);
    acc.x += __shfl_xor(acc.x, 32, 64);
    acc.y += __shfl_xor(acc.y, 32, 64);
    acc.z += __shfl_xor(acc.z, 32, 64);
    acc.w += __shfl_xor(acc.w, 32, 64);
    acc.x *= inv; acc.y *= inv; acc.z *= inv; acc.w *= inv;

    if (g == 0) {
      ((float4*)(out + ((size_t)(bq0 + qq) * NHH + e) * HH))[c] = acc;
    }
  }
}

extern "C" void kernel_launch(void* const* d_in, const int* in_sizes, int n_in,
                              void* d_out, int out_size, void* d_ws,
                              size_t ws_size, hipStream_t stream) {
  const float* q = (const float*)d_in[0];
  const float* k = (const float*)d_in[1];
  const float* v = (const float*)d_in[2];
  const int* idx = (const int*)d_in[3];
  float* out = (float*)d_out;

  // B*S*NH = 32768 query-head pairs; 2 per wave, 4 waves per block.
  const int n_blocks = (BB * SS * NHH) / 8;   // 4096
  rand_attn_kernel<<<n_blocks, 256, 0, stream>>>(q, k, v, idx, out);
}

// Round 5
// 113.694 us; speedup vs baseline: 1.4323x; 1.4323x over previous
//
#include <hip/hip_runtime.h>

// RandomAttention: B=2, S=2048, NH=8, H=64, NKEYS=64, fp32.
// R5: 8-lane-group layout. sub = lane>>3 picks the key (iteration j
// handles keys 8j..8j+7, one per subgroup); h8 = lane&7 picks two
// float4 chunks of the 256B row (bytes 16*h8 and 128+16*h8). Each
// K/V load instruction covers 8 rows x 128B, fully used. Score
// reduce is 3 DPP shuffles (xor 1,2,4) instead of 4; exp chain and
// bpermute count halve; sc[] shrinks 16->8 regs.
//
// Kept from R1: head-major XCD mapping (e = blockIdx.x & 7) pins each
// head's 2MB k+v gather slice in one XCD's 4MB L2 (FETCH 60->16.4MB).
// Kept from R2: V loads issued before softmax (best-measured order),
// exp2-domain softmax (log2e folded into q scale), deferred
// normalization, v_rcp_f32.
// Lessons: R3 (asm-forced 16-deep) and R4 (dual-query, spilled to
// scratch: WRITE 8->131MB) both regressed - stay within the RA budget
// and let the compiler own the schedule.

#define BB 2
#define SS 2048
#define NHH 8
#define HH 64
#define NKEYS 64

__global__ __launch_bounds__(256, 4) void rand_attn_kernel(
    const float* __restrict__ q, const float* __restrict__ k,
    const float* __restrict__ v, const int* __restrict__ idx,
    float* __restrict__ out) {
  const int warp = threadIdx.x >> 6;
  const int lane = threadIdx.x & 63;
  const int sub = lane >> 3;   // key subgroup: iter j handles key 8j+sub
  const int h8 = lane & 7;     // which 16B of each 128B half-row

  // Head == XCD (blocks dispatch round-robin over 8 XCDs).
  const int e = blockIdx.x & 7;                     // head
  const int bq = ((blockIdx.x >> 3) << 2) + warp;   // b*S + s, 4 per block
  const int b = bq >> 11;                           // S = 2048

  // q: this lane's two float4 chunks, pre-scaled into exp2 domain.
  const float* qrow = q + ((size_t)bq * NHH + e) * HH;
  const float qs = 0.125f * 1.44269504088896f;
  float4 qa = ((const float4*)qrow)[h8];       // floats [4h8, 4h8+4)
  float4 qb = ((const float4*)qrow)[8 + h8];   // floats [32+4h8, ...)
  qa.x *= qs; qa.y *= qs; qa.z *= qs; qa.w *= qs;
  qb.x *= qs; qb.y *= qs; qb.z *= qs; qb.w *= qs;

  // Lane n holds idx[bq, n] (coalesced 256B load).
  const int myidx = idx[(size_t)bq * NKEYS + lane];
  const float4* kb4 = (const float4*)(k + (size_t)b * (SS * NHH * HH));
  const float4* vb4 = (const float4*)(v + (size_t)b * (SS * NHH * HH));
  // Row base for key vi: (vi*NHH + e)*HH floats = vi*128 + e*16 float4.
  const int coA = (e << 4) + h8;   // chunk a: float4 index h8
  const int coB = coA + 8;         // chunk b: float4 index 8+h8

  // All 8 key-row float4-offsets (8 bpermutes vs 16 before).
  int foff[8];
#pragma unroll
  for (int j = 0; j < 8; ++j) {
    const int n = 8 * j + sub;
    const int vi = __builtin_amdgcn_ds_bpermute(n << 2, myidx);
    foff[j] = (vi << 7);
  }

  // Phase 1: K gather + dots. Per iter: 2 loads (8 rows x 128B, fully
  // used), 8 FMA, 3 DPP shuffles (reduce over the 8 lanes of a row).
  float sc[8];
#pragma unroll
  for (int j = 0; j < 8; ++j) {
    float4 ka = kb4[foff[j] + coA];
    float4 kc = kb4[foff[j] + coB];
    float t = ka.x * qa.x + ka.y * qa.y + ka.z * qa.z + ka.w * qa.w +
              kc.x * qb.x + kc.y * qb.y + kc.z * qb.z + kc.w * qb.w;
    t += __shfl_xor(t, 1, 64);
    t += __shfl_xor(t, 2, 64);
    t += __shfl_xor(t, 4, 64);
    sc[j] = t;   // score of key 8j+sub (all 8 lanes of subgroup agree)
  }

  // Phase 2a: V loads issued before softmax (latency hidden under it).
  float4 va[8], vc[8];
#pragma unroll
  for (int j = 0; j < 8; ++j) {
    va[j] = vb4[foff[j] + coA];
    vc[j] = vb4[foff[j] + coB];
  }

  // Phase 2b: softmax over all 64 keys (8 per lane + cross-subgroup).
  float m = sc[0];
#pragma unroll
  for (int j = 1; j < 8; ++j) m = fmaxf(m, sc[j]);
  m = fmaxf(m, __shfl_xor(m, 8, 64));
  m = fmaxf(m, __shfl_xor(m, 16, 64));
  m = fmaxf(m, __shfl_xor(m, 32, 64));
  float ssum = 0.f;
#pragma unroll
  for (int j = 0; j < 8; ++j) {
    sc[j] = exp2f(sc[j] - m);
    ssum += sc[j];
  }
  ssum += __shfl_xor(ssum, 8, 64);
  ssum += __shfl_xor(ssum, 16, 64);
  ssum += __shfl_xor(ssum, 32, 64);
  const float inv = __builtin_amdgcn_rcpf(ssum);  // wave-uniform

  // Phase 3: PV. Each lane accumulates its subgroup's 8 keys into its
  // two float4 chunks, then 3 cross-subgroup reduce stages.
  float4 aa = make_float4(0.f, 0.f, 0.f, 0.f);
  float4 ab = make_float4(0.f, 0.f, 0.f, 0.f);
#pragma unroll
  for (int j = 0; j < 8; ++j) {
    aa.x += sc[j] * va[j].x; aa.y += sc[j] * va[j].y;
    aa.z += sc[j] * va[j].z; aa.w += sc[j] * va[j].w;
    ab.x += sc[j] * vc[j].x; ab.y += sc[j] * vc[j].y;
    ab.z += sc[j] * vc[j].z; ab.w += sc[j] * vc[j].w;
  }
#pragma unroll
  for (int mask = 8; mask <= 32; mask <<= 1) {
    aa.x += __shfl_xor(aa.x, mask, 64); aa.y += __shfl_xor(aa.y, mask, 64);
    aa.z += __shfl_xor(aa.z, mask, 64); aa.w += __shfl_xor(aa.w, mask, 64);
    ab.x += __shfl_xor(ab.x, mask, 64); ab.y += __shfl_xor(ab.y, mask, 64);
    ab.z += __shfl_xor(ab.z, mask, 64); ab.w += __shfl_xor(ab.w, mask, 64);
  }
  aa.x *= inv; aa.y *= inv; aa.z *= inv; aa.w *= inv;
  ab.x *= inv; ab.y *= inv; ab.z *= inv; ab.w *= inv;

  if (sub == 0) {
    float4* orow = (float4*)(out + ((size_t)bq * NHH + e) * HH);
    orow[h8] = aa;       // bytes 16*h8
    orow[8 + h8] = ab;   // bytes 128+16*h8
  }
}

extern "C" void kernel_launch(void* const* d_in, const int* in_sizes, int n_in,
                              void* d_out, int out_size, void* d_ws,
                              size_t ws_size, hipStream_t stream) {
  const float* q = (const float*)d_in[0];
  const float* k = (const float*)d_in[1];
  const float* v = (const float*)d_in[2];
  const int* idx = (const int*)d_in[3];
  float* out = (float*)d_out;

  // B*S*NH = 32768 waves; 4 waves per 256-thread block -> 8192 blocks.
  const int n_blocks = (BB * SS * NHH) / 4;
  rand_attn_kernel<<<n_blocks, 256, 0, stream>>>(q, k, v, idx, out);
}